// Round 4
// baseline (247.518 us; speedup 1.0000x reference)
//
#include <hip/hip_runtime.h>
#include <math.h>

// ---------------------------------------------------------------------------
// Problem: B=64 batches. a_p = a@W1^T + b1 [64,1024]; b_p = b@W2^T + b2.
// cost[b,i,j] = (a_p[b,i]-b_p[b,j])^2 ; DTW DP R[i,j]=cost+min(diag,up,left);
// out[b] = R[1023,1023].
// ---------------------------------------------------------------------------

#define L 1024
#define BATCH 64

// ---------------- GEMM: out[b,i] = sum_k X[b,k]*W[i,k] + bias[i] -----------
__global__ __launch_bounds__(256) void proj_kernel(
    const float* __restrict__ a, const float* __restrict__ b,
    const float* __restrict__ W1, const float* __restrict__ b1,
    const float* __restrict__ W2, const float* __restrict__ b2,
    float* __restrict__ ap, float* __restrict__ bp) {
  int blk = blockIdx.x;
  const float* X;
  const float* W;
  const float* bias;
  float* out;
  int i0;
  if (blk < 64) {
    X = a; W = W1; bias = b1; out = ap; i0 = blk * 16;
  } else {
    X = b; W = W2; bias = b2; out = bp; i0 = (blk - 64) * 16;
  }

  __shared__ float a_s[64][33];
  __shared__ float w_s[16][33];

  int tid = threadIdx.x;
  int lane_b = tid & 63;
  int iq = tid >> 6;

  float acc[4] = {0.f, 0.f, 0.f, 0.f};

  for (int k0 = 0; k0 < L; k0 += 32) {
    {
      int row = tid >> 2;
      int kl = (tid & 3) * 8;
      const float4* src = reinterpret_cast<const float4*>(&X[row * L + k0 + kl]);
      float4 v0 = src[0];
      float4 v1 = src[1];
      a_s[row][kl + 0] = v0.x; a_s[row][kl + 1] = v0.y;
      a_s[row][kl + 2] = v0.z; a_s[row][kl + 3] = v0.w;
      a_s[row][kl + 4] = v1.x; a_s[row][kl + 5] = v1.y;
      a_s[row][kl + 6] = v1.z; a_s[row][kl + 7] = v1.w;
    }
    {
      int row = tid >> 4;
      int kl = (tid & 15) * 2;
      float2 v = *reinterpret_cast<const float2*>(&W[(i0 + row) * L + k0 + kl]);
      w_s[row][kl] = v.x;
      w_s[row][kl + 1] = v.y;
    }
    __syncthreads();
    #pragma unroll 8
    for (int kl = 0; kl < 32; ++kl) {
      float av = a_s[lane_b][kl];
      #pragma unroll
      for (int m = 0; m < 4; ++m) {
        acc[m] += av * w_s[iq * 4 + m][kl];
      }
    }
    __syncthreads();
  }

  #pragma unroll
  for (int m = 0; m < 4; ++m) {
    int i = i0 + iq * 4 + m;
    out[lane_b * L + i] = acc[m] + bias[i];
  }
}

// ---------------- DTW: 4 waves per batch, systolic ------------------------
// Block b handles batch b with W=4 waves x 64 lanes; lane (w,t) owns CPL=4
// columns starting at (w*64+t)*4. Lane delay D = w*OFF + t rows (OFF=64+Δ,
// Δ=3 extra rows of inter-wave skew). At step s, lane processes row i = s-D.
// Within a wave the left-boundary value moves lane t-1 -> t via DPP
// wave_shr:1. Across waves it moves through a small LDS ring buffer written
// by lane 63 and prefetched (depth 2) by lane 0 of the next wave; the
// per-step __syncthreads() guarantees write->read ordering (value for row r
// is written 2 barriers before the prefetch read is issued).

#define NW 4
#define CPL 4
#define DELTA 3
#define OFF (64 + DELTA)          // 67
#define DMAX (OFF * (NW - 1) + 63)  // 264
#define NSTEPS (L + DMAX)         // 1288
#define APPAD (DMAX + L + 320)    // covers index DMAX - D + s + 2 for all D,s

__device__ __forceinline__ float wave_shr1(float v, float fill) {
  // dpp_ctrl 0x138 = wave_shr:1 (lane i reads lane i-1); lane 0 keeps `old`.
  int r = __builtin_amdgcn_update_dpp(__float_as_int(fill), __float_as_int(v),
                                      0x138, 0xf, 0xf, false);
  return __int_as_float(r);
}

__device__ __forceinline__ float min3f(float x, float y, float z) {
  float r;
  asm("v_min3_f32 %0, %1, %2, %3" : "=v"(r) : "v"(x), "v"(y), "v"(z));
  return r;
}

__global__ __launch_bounds__(256) void dtw_kernel(const float* __restrict__ ap,
                                                  const float* __restrict__ bp,
                                                  float* __restrict__ out) {
  const int b = blockIdx.x;
  const int tid = threadIdx.x;
  const int w = tid >> 6;   // wave 0..3
  const int t = tid & 63;   // lane 0..63
  const int D = w * OFF + t;  // my delay in rows
  const float INF = INFINITY;

  // ap_pad[DMAX + i] = ap[b, i]; zero skirts -> no clamping anywhere.
  __shared__ float ap_pad[APPAD];
  __shared__ float ring[NW - 1][16];  // ring[w] : boundary wave w -> w+1

  for (int idx = tid; idx < APPAD; idx += 256) {
    int src = idx - DMAX;
    float v = 0.f;
    if (src >= 0 && src < L) v = ap[b * L + src];
    ap_pad[idx] = v;
  }

  float bpv[CPL];
  {
    float4 v = *reinterpret_cast<const float4*>(&bp[b * L + tid * CPL]);
    bpv[0] = v.x; bpv[1] = v.y; bpv[2] = v.z; bpv[3] = v.w;
  }
  float prev[CPL];
  #pragma unroll
  for (int m = 0; m < CPL; ++m) prev[m] = INF;

  __syncthreads();

  const float* apl = &ap_pad[DMAX - D];  // apl[s] == ap[b, s - D] (0 skirts)

  float right = INF;      // my x[CPL-1] of the row I last processed
  float prev_left = INF;  // R[i-1, leftcol-1]
  float pf0 = apl[0];
  float pf1 = apl[1];
  float rpf0 = INF, rpf1 = INF;  // ring prefetch queue (lane 0 of wave>0)

  const bool is_cons = (t == 0) && (w > 0);
  const bool is_prod = (t == 63) && (w < NW - 1);

  // One systolic step. PRED=true: apply row-range predicates (ramp/drain).
#define DTW_STEP(s, PRED)                                                    \
  {                                                                          \
    float left = wave_shr1(right, INF);                                      \
    int i = (s) - D;                                                         \
    float apv = pf0;                                                         \
    pf0 = pf1;                                                               \
    pf1 = apl[(s) + 2];                                                      \
    float rleft = rpf0;                                                      \
    rpf0 = rpf1;                                                             \
    if (is_cons) {                                                           \
      if (!(PRED) || (unsigned)(i + 2) < (unsigned)L)                        \
        rpf1 = ring[w - 1][(i + 2) & 15];                                    \
      left = rleft;                                                          \
    }                                                                        \
    if (t == 0 && w == 0) left = (i == 0) ? 0.f : INF;                       \
    if (!(PRED) || (unsigned)i < (unsigned)L) {                              \
      float dprev = prev_left;                                               \
      prev_left = left;                                                      \
      float d[CPL];                                                          \
      _Pragma("unroll")                                                      \
      for (int m = 0; m < CPL; ++m) d[m] = apv - bpv[m];                     \
      float x = left;                                                        \
      _Pragma("unroll")                                                      \
      for (int m = 0; m < CPL; ++m) {                                        \
        float cur = prev[m];                                                 \
        float best = min3f(cur, dprev, x);                                   \
        x = __builtin_fmaf(d[m], d[m], best);                                \
        dprev = cur;                                                         \
        prev[m] = x;                                                         \
      }                                                                      \
      right = x;                                                             \
      if (is_prod) ring[w][i & 15] = right;                                  \
    }                                                                        \
    __syncthreads();                                                         \
  }

  // Phase 1: ramp-up — some lanes not yet active.
  for (int s = 0; s < DMAX; ++s) DTW_STEP(s, true);
  // Phase 2: steady state — all 256 lanes active, no predicates.
  for (int s = DMAX; s < L; ++s) DTW_STEP(s, false);
  // Phase 3: drain.
  for (int s = L; s < NSTEPS; ++s) DTW_STEP(s, true);
#undef DTW_STEP

  if (tid == NW * 64 - 1) out[b] = right;  // R[1023,1023]
}

extern "C" void kernel_launch(void* const* d_in, const int* in_sizes, int n_in,
                              void* d_out, int out_size, void* d_ws, size_t ws_size,
                              hipStream_t stream) {
  const float* a  = (const float*)d_in[0];
  const float* b  = (const float*)d_in[1];
  const float* W1 = (const float*)d_in[2];
  const float* b1 = (const float*)d_in[3];
  const float* W2 = (const float*)d_in[4];
  const float* b2 = (const float*)d_in[5];
  float* out = (float*)d_out;

  float* ap = (float*)d_ws;
  float* bp = ap + BATCH * L;

  proj_kernel<<<128, 256, 0, stream>>>(a, b, W1, b1, W2, b2, ap, bp);
  dtw_kernel<<<BATCH, 256, 0, stream>>>(ap, bp, out);
}

// Round 5
// 173.550 us; speedup vs baseline: 1.4262x; 1.4262x over previous
//
#include <hip/hip_runtime.h>
#include <math.h>

// ---------------------------------------------------------------------------
// Problem: B=64 batches. a_p = a@W1^T + b1 [64,1024]; b_p = b@W2^T + b2.
// cost[b,i,j] = (a_p[b,i]-b_p[b,j])^2 ; DTW DP R[i,j]=cost+min(diag,up,left);
// out[b] = R[1023,1023].
// ---------------------------------------------------------------------------

#define L 1024
#define BATCH 64

// ---------------- GEMM: out[b,i] = sum_k X[b,k]*W[i,k] (+ bias) ------------
// K-split into `parts`: grid = 128*parts blocks; part p handles k in
// [p*KC, (p+1)*KC) and writes its partial to out + p*BATCH*L. Part 0 adds
// bias. dtw sums the partials while loading (no atomics -> deterministic).
__global__ __launch_bounds__(256) void proj_kernel(
    const float* __restrict__ a, const float* __restrict__ b,
    const float* __restrict__ W1, const float* __restrict__ b1,
    const float* __restrict__ W2, const float* __restrict__ b2,
    float* __restrict__ ap, float* __restrict__ bp, int KC) {
  int part = blockIdx.x >> 7;
  int sub = blockIdx.x & 127;
  const float* X;
  const float* W;
  const float* bias;
  float* out;
  int i0;
  if (sub < 64) {
    X = a; W = W1; bias = b1; out = ap + part * BATCH * L; i0 = sub * 16;
  } else {
    X = b; W = W2; bias = b2; out = bp + part * BATCH * L; i0 = (sub - 64) * 16;
  }

  __shared__ float a_s[64][33];
  __shared__ float w_s[16][33];

  int tid = threadIdx.x;
  int lane_b = tid & 63;
  int iq = tid >> 6;

  float acc[4] = {0.f, 0.f, 0.f, 0.f};

  int kbeg = part * KC;
  int kend = kbeg + KC;
  for (int k0 = kbeg; k0 < kend; k0 += 32) {
    {
      int row = tid >> 2;
      int kl = (tid & 3) * 8;
      const float4* src = reinterpret_cast<const float4*>(&X[row * L + k0 + kl]);
      float4 v0 = src[0];
      float4 v1 = src[1];
      a_s[row][kl + 0] = v0.x; a_s[row][kl + 1] = v0.y;
      a_s[row][kl + 2] = v0.z; a_s[row][kl + 3] = v0.w;
      a_s[row][kl + 4] = v1.x; a_s[row][kl + 5] = v1.y;
      a_s[row][kl + 6] = v1.z; a_s[row][kl + 7] = v1.w;
    }
    {
      int row = tid >> 4;
      int kl = (tid & 15) * 2;
      float2 v = *reinterpret_cast<const float2*>(&W[(i0 + row) * L + k0 + kl]);
      w_s[row][kl] = v.x;
      w_s[row][kl + 1] = v.y;
    }
    __syncthreads();
    #pragma unroll 8
    for (int kl = 0; kl < 32; ++kl) {
      float av = a_s[lane_b][kl];
      #pragma unroll
      for (int m = 0; m < 4; ++m) {
        acc[m] += av * w_s[iq * 4 + m][kl];
      }
    }
    __syncthreads();
  }

  #pragma unroll
  for (int m = 0; m < 4; ++m) {
    int i = i0 + iq * 4 + m;
    float bv = (part == 0) ? bias[i] : 0.f;
    out[lane_b * L + i] = acc[m] + bv;
  }
}

// ---------------- DTW: 4 waves per batch, systolic, barrier every 32 -------
// Lane (w,t) owns CPL=4 columns starting at (w*64+t)*4; delay D = w*OFF + t.
// At step s lane processes row i = s-D. Intra-wave boundary via DPP
// wave_shr:1; inter-wave via LDS ring (depth 64) written by lane 63,
// prefetched depth-3 by lane 0 of the next wave. With skew DELTA=34 every
// ring write precedes its read by exactly 32 steps = one barrier group, so a
// __syncthreads() every K=32 steps guarantees ordering (write in group g,
// read in group g+1; slot reuse distance 64 steps = 2 groups).

#define NW 4
#define CPL 4
#define KBAR 32
#define DELTA (KBAR + 2)            // 34
#define OFF (64 + DELTA)            // 98
#define DMAX (OFF * (NW - 1) + 63)  // 357
#define NG 44                       // ceil((L + DMAX) / KBAR) = 44
#define NSTEPS_R (NG * KBAR)        // 1408
#define APPAD (DMAX + NSTEPS_R + 11)

__device__ __forceinline__ float wave_shr1(float v, float fill) {
  // dpp_ctrl 0x138 = wave_shr:1 (lane i reads lane i-1); lane 0 keeps `old`.
  int r = __builtin_amdgcn_update_dpp(__float_as_int(fill), __float_as_int(v),
                                      0x138, 0xf, 0xf, false);
  return __int_as_float(r);
}

__device__ __forceinline__ float min3f(float x, float y, float z) {
  float r;
  asm("v_min3_f32 %0, %1, %2, %3" : "=v"(r) : "v"(x), "v"(y), "v"(z));
  return r;
}

__global__ __launch_bounds__(256) void dtw_kernel(const float* __restrict__ app,
                                                  const float* __restrict__ bpp,
                                                  float* __restrict__ out,
                                                  int parts) {
  const int b = blockIdx.x;
  const int tid = threadIdx.x;
  const int w = tid >> 6;
  const int t = tid & 63;
  const int D = w * OFF + t;
  const float INF = INFINITY;

  __shared__ float ap_pad[APPAD];
  __shared__ float ring[NW - 1][64];

  // ap_pad[DMAX + i] = sum_p ap_part[p][b,i]; zero skirts.
  for (int idx = tid; idx < APPAD; idx += 256) {
    int src = idx - DMAX;
    float v = 0.f;
    if (src >= 0 && src < L) {
      v = app[b * L + src];
      for (int p = 1; p < parts; ++p) v += app[p * BATCH * L + b * L + src];
    }
    ap_pad[idx] = v;
  }

  float bpv[CPL];
  {
    float4 v = *reinterpret_cast<const float4*>(&bpp[b * L + tid * CPL]);
    for (int p = 1; p < parts; ++p) {
      float4 u = *reinterpret_cast<const float4*>(
          &bpp[p * BATCH * L + b * L + tid * CPL]);
      v.x += u.x; v.y += u.y; v.z += u.z; v.w += u.w;
    }
    bpv[0] = v.x; bpv[1] = v.y; bpv[2] = v.z; bpv[3] = v.w;
  }
  float prev[CPL];
  #pragma unroll
  for (int m = 0; m < CPL; ++m) prev[m] = INF;

  __syncthreads();

  const float* apl = &ap_pad[DMAX - D];  // apl[s] == ap[b, s - D] (0 skirts)

  float right = INF;
  float prev_left = INF;
  float pf0 = apl[0], pf1 = apl[1], pf2 = apl[2];
  float rpf0 = INF, rpf1 = INF, rpf2 = INF;

  const bool is_cons = (t == 0) && (w > 0);
  const bool is_prod = (t == 63) && (w < NW - 1);

  // Predicated step (ramp/drain).
#define STEP_PRED(s)                                                         \
  {                                                                          \
    float left = wave_shr1(right, INF);                                      \
    int i = (s) - D;                                                         \
    float apv = pf0;                                                         \
    pf0 = pf1; pf1 = pf2; pf2 = apl[(s) + 3];                                \
    float rleft = rpf0;                                                      \
    rpf0 = rpf1; rpf1 = rpf2;                                                \
    if (is_cons) {                                                           \
      if ((unsigned)(i + 3) < (unsigned)L)                                   \
        rpf2 = ring[w - 1][(i + 3) & 63];                                    \
      left = rleft;                                                          \
    }                                                                        \
    if (t == 0 && w == 0) left = (i == 0) ? 0.f : INF;                       \
    if ((unsigned)i < (unsigned)L) {                                         \
      float dprev = prev_left;                                               \
      prev_left = left;                                                      \
      float d[CPL];                                                          \
      _Pragma("unroll")                                                      \
      for (int m = 0; m < CPL; ++m) d[m] = apv - bpv[m];                     \
      float x = left;                                                        \
      _Pragma("unroll")                                                      \
      for (int m = 0; m < CPL; ++m) {                                        \
        float cur = prev[m];                                                 \
        float best = min3f(cur, dprev, x);                                   \
        x = __builtin_fmaf(d[m], d[m], best);                                \
        dprev = cur;                                                         \
        prev[m] = x;                                                         \
      }                                                                      \
      right = x;                                                             \
      if (is_prod) ring[w][i & 63] = right;                                  \
    }                                                                        \
  }

  // Steady step: all lanes active, no predicates, no lane-0 fixup (the DPP
  // `old` operand keeps lane (0,0)'s left at INF; prev_left self-maintains).
#define STEP_FAST(s)                                                         \
  {                                                                          \
    float left = wave_shr1(right, INF);                                      \
    int i = (s) - D;                                                         \
    float apv = pf0;                                                         \
    pf0 = pf1; pf1 = pf2; pf2 = apl[(s) + 3];                                \
    float rleft = rpf0;                                                      \
    rpf0 = rpf1; rpf1 = rpf2;                                                \
    if (is_cons) {                                                           \
      rpf2 = ring[w - 1][(i + 3) & 63];                                      \
      left = rleft;                                                          \
    }                                                                        \
    float dprev = prev_left;                                                 \
    prev_left = left;                                                        \
    float d[CPL];                                                            \
    _Pragma("unroll")                                                        \
    for (int m = 0; m < CPL; ++m) d[m] = apv - bpv[m];                       \
    float x = left;                                                          \
    _Pragma("unroll")                                                        \
    for (int m = 0; m < CPL; ++m) {                                          \
      float cur = prev[m];                                                   \
      float best = min3f(cur, dprev, x);                                     \
      x = __builtin_fmaf(d[m], d[m], best);                                  \
      dprev = cur;                                                           \
      prev[m] = x;                                                           \
    }                                                                        \
    right = x;                                                               \
    if (is_prod) ring[w][i & 63] = right;                                    \
  }

  // Ramp: groups 0..11 (steps 0..383 >= DMAX=357 covered predicated).
  for (int g = 0; g < 12; ++g) {
    int s0 = g * KBAR;
    #pragma unroll 4
    for (int k = 0; k < KBAR; ++k) STEP_PRED(s0 + k);
    __syncthreads();
  }
  // Steady: groups 12..31 (steps 384..1023; i in [0,L) for every lane).
  for (int g = 12; g < 32; ++g) {
    int s0 = g * KBAR;
    #pragma unroll 4
    for (int k = 0; k < KBAR; ++k) STEP_FAST(s0 + k);
    __syncthreads();
  }
  // Drain: groups 32..43 (steps 1024..1407).
  for (int g = 32; g < NG; ++g) {
    int s0 = g * KBAR;
    #pragma unroll 4
    for (int k = 0; k < KBAR; ++k) STEP_PRED(s0 + k);
    __syncthreads();
  }
#undef STEP_PRED
#undef STEP_FAST

  if (tid == NW * 64 - 1) out[b] = right;  // R[1023,1023]
}

extern "C" void kernel_launch(void* const* d_in, const int* in_sizes, int n_in,
                              void* d_out, int out_size, void* d_ws, size_t ws_size,
                              hipStream_t stream) {
  const float* a  = (const float*)d_in[0];
  const float* b  = (const float*)d_in[1];
  const float* W1 = (const float*)d_in[2];
  const float* b1 = (const float*)d_in[3];
  const float* W2 = (const float*)d_in[4];
  const float* b2 = (const float*)d_in[5];
  float* out = (float*)d_out;

  // K-split factor limited by workspace: each part needs 2*BATCH*L floats.
  size_t per_part = (size_t)2 * BATCH * L * sizeof(float);
  int parts = 1;
  if (ws_size >= 4 * per_part) parts = 4;
  else if (ws_size >= 2 * per_part) parts = 2;

  float* ap = (float*)d_ws;                 // parts x [BATCH, L]
  float* bp = ap + (size_t)parts * BATCH * L;  // parts x [BATCH, L]

  proj_kernel<<<128 * parts, 256, 0, stream>>>(a, b, W1, b1, W2, b2,
                                               ap, bp, L / parts);
  dtw_kernel<<<BATCH, 256, 0, stream>>>(ap, bp, out, parts);
}

// Round 6
// 99.785 us; speedup vs baseline: 2.4805x; 1.7392x over previous
//
#include <hip/hip_runtime.h>
#include <math.h>

// ---------------------------------------------------------------------------
// Problem: B=64 batches. a_p = a@W1^T + b1 [64,1024]; b_p = b@W2^T + b2.
// cost[b,i,j] = (a_p[b,i]-b_p[b,j])^2 ; DTW DP R[i,j]=cost+min(diag,up,left);
// out[b] = R[1023,1023].
// ---------------------------------------------------------------------------

#define L 1024
#define BATCH 64

// ---------------- GEMM: out[b,i] = sum_k X[b,k]*W[i,k] (+ bias) ------------
__global__ __launch_bounds__(256) void proj_kernel(
    const float* __restrict__ a, const float* __restrict__ b,
    const float* __restrict__ W1, const float* __restrict__ b1,
    const float* __restrict__ W2, const float* __restrict__ b2,
    float* __restrict__ ap, float* __restrict__ bp, int KC) {
  int part = blockIdx.x >> 7;
  int sub = blockIdx.x & 127;
  const float* X;
  const float* W;
  const float* bias;
  float* out;
  int i0;
  if (sub < 64) {
    X = a; W = W1; bias = b1; out = ap + part * BATCH * L; i0 = sub * 16;
  } else {
    X = b; W = W2; bias = b2; out = bp + part * BATCH * L; i0 = (sub - 64) * 16;
  }

  __shared__ float a_s[64][33];
  __shared__ float w_s[16][33];

  int tid = threadIdx.x;
  int lane_b = tid & 63;
  int iq = tid >> 6;

  float acc[4] = {0.f, 0.f, 0.f, 0.f};

  int kbeg = part * KC;
  int kend = kbeg + KC;
  for (int k0 = kbeg; k0 < kend; k0 += 32) {
    {
      int row = tid >> 2;
      int kl = (tid & 3) * 8;
      const float4* src = reinterpret_cast<const float4*>(&X[row * L + k0 + kl]);
      float4 v0 = src[0];
      float4 v1 = src[1];
      a_s[row][kl + 0] = v0.x; a_s[row][kl + 1] = v0.y;
      a_s[row][kl + 2] = v0.z; a_s[row][kl + 3] = v0.w;
      a_s[row][kl + 4] = v1.x; a_s[row][kl + 5] = v1.y;
      a_s[row][kl + 6] = v1.z; a_s[row][kl + 7] = v1.w;
    }
    {
      int row = tid >> 4;
      int kl = (tid & 15) * 2;
      float2 v = *reinterpret_cast<const float2*>(&W[(i0 + row) * L + k0 + kl]);
      w_s[row][kl] = v.x;
      w_s[row][kl + 1] = v.y;
    }
    __syncthreads();
    #pragma unroll 8
    for (int kl = 0; kl < 32; ++kl) {
      float av = a_s[lane_b][kl];
      #pragma unroll
      for (int m = 0; m < 4; ++m) {
        acc[m] += av * w_s[iq * 4 + m][kl];
      }
    }
    __syncthreads();
  }

  #pragma unroll
  for (int m = 0; m < 4; ++m) {
    int i = i0 + iq * 4 + m;
    float bv = (part == 0) ? bias[i] : 0.f;
    out[lane_b * L + i] = acc[m] + bv;
  }
}

// ---------------- DTW: 4 waves/batch, systolic, LDS-free steady step -------
// Lane (w,t) owns CPL=4 columns starting at (w*64+t)*4; delay D = w*OFF + t.
// At step s lane processes row i = s-D. ALL per-step dataflow is DPP:
//   - boundary:  left = wave_shr1(right, old=ringchunk)  (lane0 <- ring feed)
//   - ap value:  apv  = wave_shr1(apv,   old=apchunk)    (lane0 <- ap feed)
//   - feeds walk toward lane 0 via wave_shl1 per step (lane0 = element k
//     after k shifts).
// Per KBAR=32-step group: 1 coalesced ds_read of the ap chunk, 1 coalesced
// ds_read of the ring chunk (consumer waves), 1 coalesced ds_write of the 32
// captured lane-63 values (producer waves), 1 __syncthreads().
// GAP = OFF-63 = 32 exactly: production of row r is 32 steps before its
// consumption -> always in the previous group (flushed, barrier-ordered),
// and read/write slot ranges within a group are disjoint 32-slot halves of
// the 64-deep ring (no same-group overlap).

#define NW 4
#define CPL 4
#define KBAR 32
#define OFF 95                       // 64 + DELTA, DELTA = 31 -> GAP = 32
#define DMAX (OFF * (NW - 1) + 63)   // 348
#define NG 43                        // ceil((L + DMAX) / KBAR)
#define NSTEPS (NG * KBAR)           // 1376
#define APPAD (DMAX + NSTEPS + 64)   // 1788

__device__ __forceinline__ float dpp_shr1(float v, float old) {
  // lane i <- lane i-1; lane 0 <- old[lane 0] (bound_ctrl=false).
  int r = __builtin_amdgcn_update_dpp(__float_as_int(old), __float_as_int(v),
                                      0x138, 0xf, 0xf, false);
  return __int_as_float(r);
}

__device__ __forceinline__ float dpp_shl1(float v) {
  // lane i <- lane i+1; lane 63 keeps its value.
  int r = __builtin_amdgcn_update_dpp(__float_as_int(v), __float_as_int(v),
                                      0x130, 0xf, 0xf, false);
  return __int_as_float(r);
}

__device__ __forceinline__ float min3f(float x, float y, float z) {
  float r;
  asm("v_min3_f32 %0, %1, %2, %3" : "=v"(r) : "v"(x), "v"(y), "v"(z));
  return r;
}

__global__ __launch_bounds__(256) void dtw_kernel(const float* __restrict__ app,
                                                  const float* __restrict__ bpp,
                                                  float* __restrict__ out,
                                                  int parts) {
  const int b = blockIdx.x;
  const int tid = threadIdx.x;
  const int w = tid >> 6;
  const int t = tid & 63;
  const int woff = w * OFF;
  const int D = woff + t;
  const float INF = INFINITY;

  __shared__ float ap_pad[APPAD];
  __shared__ float ring[NW - 1][64];

  // ap_pad[DMAX + i] = sum_p ap_part[p][b,i]; zero skirts.
  for (int idx = tid; idx < APPAD; idx += 256) {
    int src = idx - DMAX;
    float v = 0.f;
    if ((unsigned)src < (unsigned)L) {
      v = app[b * L + src];
      for (int p = 1; p < parts; ++p) v += app[p * BATCH * L + b * L + src];
    }
    ap_pad[idx] = v;
  }

  float4 bv = *reinterpret_cast<const float4*>(&bpp[b * L + tid * CPL]);
  for (int p = 1; p < parts; ++p) {
    float4 u = *reinterpret_cast<const float4*>(
        &bpp[p * BATCH * L + b * L + tid * CPL]);
    bv.x += u.x; bv.y += u.y; bv.z += u.z; bv.w += u.w;
  }
  const float bpv0 = bv.x, bpv1 = bv.y, bpv2 = bv.z, bpv3 = bv.w;

  float p0 = INF, p1 = INF, p2 = INF, p3 = INF;   // prev-row cells
  float right = INF, prev_left = INF, apv = 0.f;
  // wave 0's boundary feed: lane0=0 gives R[0,0]'s left=0 at the very first
  // step; shifts bring INF afterwards. Never reloaded for wave 0.
  float ringchunk = (w == 0 && t == 0) ? 0.f : INF;
  float apchunk = 0.f;
  float vprod = INF;
  const int ap_base = DMAX - woff + t;

  __syncthreads();

#define STEP_CORE()                                                          \
    float dprev = prev_left;                                                 \
    prev_left = left;                                                        \
    float d0 = apv - bpv0, d1 = apv - bpv1, d2 = apv - bpv2, d3 = apv - bpv3;\
    float x = left, bb;                                                      \
    bb = min3f(p0, dprev, x); x = __builtin_fmaf(d0, d0, bb); dprev = p0; p0 = x; \
    bb = min3f(p1, dprev, x); x = __builtin_fmaf(d1, d1, bb); dprev = p1; p1 = x; \
    bb = min3f(p2, dprev, x); x = __builtin_fmaf(d2, d2, bb); dprev = p2; p2 = x; \
    bb = min3f(p3, dprev, x); x = __builtin_fmaf(d3, d3, bb); p3 = x;        \
    right = x;

#define STEP_FAST()                                                          \
  {                                                                          \
    float left = dpp_shr1(right, ringchunk);                                 \
    apv = dpp_shr1(apv, apchunk);                                            \
    apchunk = dpp_shl1(apchunk);                                             \
    ringchunk = dpp_shl1(ringchunk);                                         \
    STEP_CORE();                                                             \
    vprod = dpp_shl1(vprod);                                                 \
    vprod = (t == 63) ? right : vprod;                                       \
  }

#define STEP_PRED(s)                                                         \
  {                                                                          \
    float left = dpp_shr1(right, ringchunk);                                 \
    apv = dpp_shr1(apv, apchunk);                                            \
    apchunk = dpp_shl1(apchunk);                                             \
    ringchunk = dpp_shl1(ringchunk);                                         \
    int ii = (s) - D;                                                        \
    if ((unsigned)ii < (unsigned)L) {                                        \
      STEP_CORE();                                                           \
    }                                                                        \
    vprod = dpp_shl1(vprod);                                                 \
    vprod = (t == 63) ? right : vprod;                                       \
  }

#define GROUP_LOAD(s0)                                                       \
    apchunk = ap_pad[ap_base + (s0)];                                        \
    if (w > 0 && t < KBAR)                                                   \
      ringchunk = ring[w - 1][((s0) - woff + t) & 63];

#define GROUP_STORE(s0)                                                      \
    if (w < NW - 1 && t >= 64 - KBAR)                                        \
      ring[w][((s0) - woff - 95 + t) & 63] = vprod;                          \
    __syncthreads();

  // Ramp: groups 0..10 (steps 0..351; DMAX=348 -> predicated).
  for (int g = 0; g < 11; ++g) {
    int s0 = g * KBAR;
    GROUP_LOAD(s0);
    #pragma unroll
    for (int k = 0; k < KBAR; ++k) STEP_PRED(s0 + k);
    GROUP_STORE(s0);
  }
  // Steady: groups 11..31 (steps 352..1023; all lanes i in [0,L)).
  for (int g = 11; g < 32; ++g) {
    int s0 = g * KBAR;
    GROUP_LOAD(s0);
    #pragma unroll
    for (int k = 0; k < KBAR; ++k) STEP_FAST();
    GROUP_STORE(s0);
  }
  // Drain: groups 32..42 (steps 1024..1375; lane 255 last active at 1371).
  for (int g = 32; g < NG; ++g) {
    int s0 = g * KBAR;
    GROUP_LOAD(s0);
    #pragma unroll
    for (int k = 0; k < KBAR; ++k) STEP_PRED(s0 + k);
    GROUP_STORE(s0);
  }
#undef STEP_CORE
#undef STEP_FAST
#undef STEP_PRED
#undef GROUP_LOAD
#undef GROUP_STORE

  if (tid == NW * 64 - 1) out[b] = right;  // R[1023,1023]
}

extern "C" void kernel_launch(void* const* d_in, const int* in_sizes, int n_in,
                              void* d_out, int out_size, void* d_ws, size_t ws_size,
                              hipStream_t stream) {
  const float* a  = (const float*)d_in[0];
  const float* b  = (const float*)d_in[1];
  const float* W1 = (const float*)d_in[2];
  const float* b1 = (const float*)d_in[3];
  const float* W2 = (const float*)d_in[4];
  const float* b2 = (const float*)d_in[5];
  float* out = (float*)d_out;

  size_t per_part = (size_t)2 * BATCH * L * sizeof(float);
  int parts = 1;
  if (ws_size >= 4 * per_part) parts = 4;
  else if (ws_size >= 2 * per_part) parts = 2;

  float* ap = (float*)d_ws;                    // parts x [BATCH, L]
  float* bp = ap + (size_t)parts * BATCH * L;  // parts x [BATCH, L]

  proj_kernel<<<128 * parts, 256, 0, stream>>>(a, b, W1, b1, W2, b2,
                                               ap, bp, L / parts);
  dtw_kernel<<<BATCH, 256, 0, stream>>>(ap, bp, out, parts);
}